// Round 12
// baseline (231.210 us; speedup 1.0000x reference)
//
#include <hip/hip_runtime.h>
#include <math.h>

#define LOG2E_F 1.4426950408889634f
#define LN2_F   0.6931471805599453f

constexpr int Bn = 1024;
constexpr int Tn = 512;
constexpr int Ln = 32;

typedef unsigned int uint2v __attribute__((ext_vector_type(2)));

// ---------------- shared step machinery (macros used by real + probe) -------

#if __has_builtin(__builtin_amdgcn_permlane32_swap)
#define PROBE32 \
    bool use_y32; \
    { \
        const uint2v r = __builtin_amdgcn_permlane32_swap((unsigned)l, (unsigned)l, false, false); \
        const bool selA = __all((((l < 32) ? (int)r[1] : (int)r[0]) == (l ^ 32)) ? 1 : 0); \
        use_y32 = selA ? (l < 32) : (l >= 32); \
    }
#define CROSS32(p, out) { \
    const uint2v r_ = __builtin_amdgcn_permlane32_swap( \
        __float_as_uint(p), __float_as_uint(p), false, false); \
    out = __uint_as_float(use_y32 ? r_[1] : r_[0]); }
#else
#define PROBE32
#define CROSS32(p, out) out = __shfl_xor((p), 32);
#endif

#if __has_builtin(__builtin_amdgcn_permlane16_swap)
#define PROBE16 \
    bool use_r016; \
    { \
        const uint2v r = __builtin_amdgcn_permlane16_swap((unsigned)l, (unsigned)l, false, false); \
        const bool selA = __all(((((l & 16) ? (int)r[0] : (int)r[1])) == (l ^ 16)) ? 1 : 0); \
        use_r016 = selA ? ((l & 16) != 0) : ((l & 16) == 0); \
    }
#define CROSS16(p, out) { \
    const uint2v r_ = __builtin_amdgcn_permlane16_swap( \
        __float_as_uint(p), __float_as_uint(p), false, false); \
    out = __uint_as_float(use_r016 ? r_[0] : r_[1]); }
#else
#define PROBE16
#define CROSS16(p, out) out = __int_as_float(__builtin_amdgcn_ds_swizzle( \
        __float_as_int(p), 0x401F));
#endif

#define ISS1(REG, TT) {                                                     \
    int ts_ = (TT);                                                         \
    ts_ = ts_ < 0 ? 0 : (ts_ > (Tn - 1) ? (Tn - 1) : ts_);                  \
    const unsigned voff_ = (unsigned)ts_ * (unsigned)(Ln * 4) + col4;       \
    asm volatile("global_load_dword %0, %1, %2"                             \
                 : "=v"(REG) : "v"(voff_), "s"(xb)); }

#define ISSUE16(P, TB)                                                      \
    ISS1(P##0,  (TB))            ISS1(P##1,  (TB) + 1  * dtt)               \
    ISS1(P##2,  (TB) + 2 * dtt)  ISS1(P##3,  (TB) + 3  * dtt)               \
    ISS1(P##4,  (TB) + 4 * dtt)  ISS1(P##5,  (TB) + 5  * dtt)               \
    ISS1(P##6,  (TB) + 6 * dtt)  ISS1(P##7,  (TB) + 7  * dtt)               \
    ISS1(P##8,  (TB) + 8 * dtt)  ISS1(P##9,  (TB) + 9  * dtt)               \
    ISS1(P##10, (TB) + 10 * dtt) ISS1(P##11, (TB) + 11 * dtt)               \
    ISS1(P##12, (TB) + 12 * dtt) ISS1(P##13, (TB) + 13 * dtt)               \
    ISS1(P##14, (TB) + 14 * dtt) ISS1(P##15, (TB) + 15 * dtt)

#define WAITALL(P)                                                          \
    asm volatile("s_waitcnt vmcnt(0)"                                       \
        : "+v"(P##0), "+v"(P##1), "+v"(P##2),  "+v"(P##3),                  \
          "+v"(P##4), "+v"(P##5), "+v"(P##6),  "+v"(P##7),                  \
          "+v"(P##8), "+v"(P##9), "+v"(P##10), "+v"(P##11),                 \
          "+v"(P##12), "+v"(P##13), "+v"(P##14), "+v"(P##15)                \
        : : "memory");

#define COPY16(D, S)                                                        \
    D##0 = S##0;   D##1 = S##1;   D##2 = S##2;   D##3 = S##3;               \
    D##4 = S##4;   D##5 = S##5;   D##6 = S##6;   D##7 = S##7;               \
    D##8 = S##8;   D##9 = S##9;   D##10 = S##10; D##11 = S##11;             \
    D##12 = S##12; D##13 = S##13; D##14 = S##14; D##15 = S##15;

#define ROT(T) __int_as_float(__builtin_amdgcn_update_dpp(                  \
        0, __float_as_int(xs), 0x120 + (T), 0xF, 0xF, true))

#define STEP(R, PRE, NXTV) {                                                \
    const float gcur = ggc;                                                 \
    if (PRE) ggc = __builtin_amdgcn_exp2f((NXTV) * LOG2E_F);                \
    const float xs = dir ? x * gcur : x;                                    \
    const float r1  = ROT(1);   const float r2  = ROT(2);                   \
    const float r3  = ROT(3);   const float r4  = ROT(4);                   \
    const float r5  = ROT(5);   const float r6  = ROT(6);                   \
    const float r7  = ROT(7);   const float r8  = ROT(8);                   \
    const float r9  = ROT(9);   const float r10 = ROT(10);                  \
    const float r11 = ROT(11);  const float r12 = ROT(12);                  \
    const float r13 = ROT(13);  const float r14 = ROT(14);                  \
    const float r15 = ROT(15);                                              \
    float a0 = xs * Ei[0];   float a1 = r1 * Ei[1];                         \
    float a2 = r2 * Ei[2];   float a3 = r3 * Ei[3];                         \
    a0 = fmaf(r4,  Ei[4],  a0);   a1 = fmaf(r5,  Ei[5],  a1);               \
    a2 = fmaf(r6,  Ei[6],  a2);   a3 = fmaf(r7,  Ei[7],  a3);               \
    a0 = fmaf(r8,  Ei[8],  a0);   a1 = fmaf(r9,  Ei[9],  a1);               \
    a2 = fmaf(r10, Ei[10], a2);   a3 = fmaf(r11, Ei[11], a3);               \
    a0 = fmaf(r12, Ei[12], a0);   a1 = fmaf(r13, Ei[13], a1);               \
    a2 = fmaf(r14, Ei[14], a2);   a3 = fmaf(r15, Ei[15], a3);               \
    const float partial = (a0 + a1) + (a2 + a3);                            \
    float cross; CROSS32(partial, cross)                                    \
    float full = partial + cross;                                           \
    if (dir == 0) full *= gcur;                                             \
    float fx; CROSS16(full, fx)                                             \
    const float cand = (l < 32) ? full : fx;                                \
    const bool act = ((kb + (R)) <= K);                                     \
    x = act ? cand : x;                                                     \
    if (((R) & 3) == 2) capv = x;                                           \
    if (((R) & 3) == 3) {                                                   \
        const int cb = __builtin_amdgcn_readfirstlane(                      \
            __float_as_int(fmaxf(capv, 1e-30f)));                           \
        const int ee = ((cb >> 23) & 255) - 127;                            \
        x *= __int_as_float((127 - ee) << 23);                              \
        Mr += (float)ee;                                                    \
    } }

#define STEPS16(P)                                                          \
    ggc = __builtin_amdgcn_exp2f(P##0 * LOG2E_F);                           \
    STEP(0,  1, P##1)   STEP(1,  1, P##2)   STEP(2,  1, P##3)               \
    STEP(3,  1, P##4)   STEP(4,  1, P##5)   STEP(5,  1, P##6)               \
    STEP(6,  1, P##7)   STEP(7,  1, P##8)   STEP(8,  1, P##9)               \
    STEP(9,  1, P##10)  STEP(10, 1, P##11)  STEP(11, 1, P##12)              \
    STEP(12, 1, P##13)  STEP(13, 1, P##14)  STEP(14, 1, P##15)              \
    STEP(15, 0, P##15)                                                      \
    kb += 16;

#define EI_SETUP                                                            \
    float Ei[16];                                                           \
    {                                                                       \
        float tmax = -3.4e38f;                                              \
        _Pragma("unroll")                                                   \
        for (int t = 0; t < 16; ++t) {                                      \
            const int s = ror_minus ? ((k15 - t) & 15) : ((k15 + t) & 15);  \
            const int i = 16 * ih + s;                                      \
            const float tv = dir ? trans[phi * Ln + i] : trans[i * Ln + phi]; \
            Ei[t] = tv;                                                     \
            tmax = fmaxf(tmax, tv);                                         \
        }                                                                   \
        _Pragma("unroll")                                                   \
        for (int off = 1; off < 64; off <<= 1)                              \
            tmax = fmaxf(tmax, __shfl_xor(tmax, off));                      \
        tmax2 = tmax * LOG2E_F;                                             \
        _Pragma("unroll")                                                   \
        for (int t = 0; t < 16; ++t)                                        \
            Ei[t] = __builtin_amdgcn_exp2f((Ei[t] - tmax) * LOG2E_F);       \
    }

// ---------------- real chain kernel (identical logic to round 11) ----------
__global__ __launch_bounds__(64)
void crf_chain_kernel(const float* __restrict__ logits,
                      const float* __restrict__ trans,
                      const int* __restrict__ seq_lens,
                      float* __restrict__ ws)
{
    const int blk = blockIdx.x;
    const int b   = blk >> 1;
    const int dir = blk & 1;
    const int l   = threadIdx.x;
    const int k15 = l & 15;
    const int phi = l & 31;
    const int ih  = ((l >> 4) ^ (l >> 5)) & 1;
    const int pi  = phi ^ ((l >> 5) << 4);

    int len = seq_lens[b];
    len = len < 1 ? 1 : (len > Tn ? Tn : len);
    const int m  = (len + 1) >> 1;
    const int K  = dir ? (len - m) : (m - 1);
    const int ngroups = (K + 15) >> 4;

    const float* xb = logits + (size_t)b * (Tn * Ln);

    const int w0 = __builtin_amdgcn_readfirstlane(
        __builtin_amdgcn_update_dpp(0, l, 0x121, 0xF, 0xF, true));
    const bool ror_minus = (w0 == 15);
    PROBE32
    PROBE16

    float tmax2;
    EI_SETUP

    float x, Minit;
    if (dir == 0) {
        const float a0v = xb[pi] * LOG2E_F;
        float mx = a0v;
        #pragma unroll
        for (int off = 1; off < 64; off <<= 1)
            mx = fmaxf(mx, __shfl_xor(mx, off));
        x = __builtin_amdgcn_exp2f(a0v - mx);
        Minit = mx;
    } else {
        x = 1.0f;
        Minit = 0.0f;
    }
    float Mr = 0.0f;
    float capv = x;

    const int loadlab = dir ? pi : phi;
    const unsigned col4 = (unsigned)loadlab * 4u;
    const int dtt = dir ? -1 : 1;
    const int t0  = dir ? (len - 1) : 1;

    float A0, A1, A2, A3, A4, A5, A6, A7;
    float A8, A9, A10, A11, A12, A13, A14, A15;
    float B0, B1, B2, B3, B4, B5, B6, B7;
    float B8, B9, B10, B11, B12, B13, B14, B15;

    float ggc = 1.0f;
    int kb = 1;

    ISSUE16(B, t0)
    WAITALL(B)
    COPY16(A, B)
    int tnext = t0 + 16 * dtt;

    for (int g = 0; g < ngroups; ++g) {
        ISSUE16(B, tnext)
        tnext += 16 * dtt;
        __builtin_amdgcn_sched_barrier(0);
        STEPS16(A)
        __builtin_amdgcn_sched_barrier(0);
        WAITALL(B)
        __builtin_amdgcn_sched_barrier(0);
        COPY16(A, B)
    }

    asm volatile("s_waitcnt vmcnt(0)" ::: "memory");

    const float M = Minit + (float)K * tmax2 + Mr;

    float* wsrow = ws + (size_t)(b * 2 + dir) * 33;
    if (l < 32) wsrow[l] = x;
    if (l == 0) wsrow[32] = M;
}

// ---------------- diagnostic probes (results overwritten by real kernel) ---
// V=1: full step + real load pipeline, uniform NSTEP (isolates imbalance/tail)
// V=2: full step, loads removed (register emissions)
// V=4: crosses only
template<int V, int NSTEP>
__global__ __launch_bounds__(64)
void crf_probe_kernel(const float* __restrict__ logits,
                      const float* __restrict__ trans,
                      float* __restrict__ ws)
{
    const int blk = blockIdx.x;
    const int b   = blk >> 1;
    const int dir = blk & 1;
    const int l   = threadIdx.x;
    const int k15 = l & 15;
    const int phi = l & 31;
    const int ih  = ((l >> 4) ^ (l >> 5)) & 1;
    const int pi  = phi ^ ((l >> 5) << 4);

    const float* xb = logits + (size_t)b * (Tn * Ln);

    const int w0 = __builtin_amdgcn_readfirstlane(
        __builtin_amdgcn_update_dpp(0, l, 0x121, 0xF, 0xF, true));
    const bool ror_minus = (w0 == 15);
    PROBE32
    PROBE16

    float tmax2;
    EI_SETUP
    (void)tmax2;

    float x = 1.0f + (float)pi * 0.015625f;
    float Mr = 0.0f;
    float capv = x;
    const int K = NSTEP + 1;          // act always true (cost parity)
    int kb = 1;
    float ggc = 1.0f;

    if constexpr (V == 1) {
        const unsigned col4 = (unsigned)(dir ? pi : phi) * 4u;
        const int dtt = 1;
        float A0, A1, A2, A3, A4, A5, A6, A7;
        float A8, A9, A10, A11, A12, A13, A14, A15;
        float B0, B1, B2, B3, B4, B5, B6, B7;
        float B8, B9, B10, B11, B12, B13, B14, B15;
        ISSUE16(B, 0)
        WAITALL(B)
        COPY16(A, B)
        int tnext = 16;
        for (int g = 0; g < NSTEP / 16; ++g) {
            ISSUE16(B, tnext)
            tnext += 16;
            if (tnext > Tn - 17) tnext = 0;     // stay in-bounds, keep streaming
            __builtin_amdgcn_sched_barrier(0);
            STEPS16(A)
            __builtin_amdgcn_sched_barrier(0);
            WAITALL(B)
            __builtin_amdgcn_sched_barrier(0);
            COPY16(A, B)
        }
        asm volatile("s_waitcnt vmcnt(0)" ::: "memory");
    } else if constexpr (V == 2) {
        // register-fed emissions, exact same STEPS16 instruction stream
        float F0  = 1.00f + (float)((pi * 7 + 0)  & 31) * 0.01f;
        float F1  = 1.00f + (float)((pi * 7 + 3)  & 31) * 0.01f;
        float F2  = 1.00f + (float)((pi * 7 + 6)  & 31) * 0.01f;
        float F3  = 1.00f + (float)((pi * 7 + 9)  & 31) * 0.01f;
        float F4  = 1.00f + (float)((pi * 7 + 12) & 31) * 0.01f;
        float F5  = 1.00f + (float)((pi * 7 + 15) & 31) * 0.01f;
        float F6  = 1.00f + (float)((pi * 7 + 18) & 31) * 0.01f;
        float F7  = 1.00f + (float)((pi * 7 + 21) & 31) * 0.01f;
        float F8  = 1.00f + (float)((pi * 7 + 24) & 31) * 0.01f;
        float F9  = 1.00f + (float)((pi * 7 + 27) & 31) * 0.01f;
        float F10 = 1.00f + (float)((pi * 7 + 30) & 31) * 0.01f;
        float F11 = 1.00f + (float)((pi * 7 + 1)  & 31) * 0.01f;
        float F12 = 1.00f + (float)((pi * 7 + 4)  & 31) * 0.01f;
        float F13 = 1.00f + (float)((pi * 7 + 7)  & 31) * 0.01f;
        float F14 = 1.00f + (float)((pi * 7 + 10) & 31) * 0.01f;
        float F15 = 1.00f + (float)((pi * 7 + 13) & 31) * 0.01f;
        for (int g = 0; g < NSTEP / 16; ++g) {
            STEPS16(F)
        }
    } else {
        // V == 4: crosses only
        for (int g = 0; g < NSTEP / 16; ++g) {
            #pragma unroll
            for (int r = 0; r < 16; ++r) {
                float cr; CROSS32(x, cr)
                const float s = x + cr;
                float fx; CROSS16(s, fx)
                const float cand = (l < 32) ? s : fx;
                // force exponent to [1,2): stability w/o renorm, keeps dataflow
                x = __int_as_float((__float_as_int(cand) & 0x007fffff) | 0x3f800000);
            }
        }
    }

    if (l == 0) ws[(size_t)blk * 33] = x + Mr * 1e-30f;
}

// ---------------- combine kernel (unchanged) --------------------------------
__global__ __launch_bounds__(64)
void crf_combine_kernel(const float* __restrict__ logits,
                        const float* __restrict__ trans,
                        const int* __restrict__ labels,
                        const int* __restrict__ seq_lens,
                        const float* __restrict__ ws,
                        float* __restrict__ out)
{
    const int b    = blockIdx.x;
    const int lane = threadIdx.x;
    const int j    = lane & 31;

    int len = seq_lens[b];
    len = len < 1 ? 1 : (len > Tn ? Tn : len);

    const int*   lb = labels + (size_t)b * Tn;
    const float* xb = logits + (size_t)b * (Tn * Ln);

    float acc = 0.f;
    for (int t = lane; t < len; t += 64) {
        const int lt = lb[t];
        acc += xb[t * Ln + lt];
        if (t >= 1) acc += trans[lb[t - 1] * Ln + lt];
    }
    #pragma unroll
    for (int off = 1; off < 64; off <<= 1)
        acc += __shfl_xor(acc, off);

    const float* wf = ws + (size_t)(b * 2 + 0) * 33;
    const float* wb = ws + (size_t)(b * 2 + 1) * 33;
    float term = wf[j] * wb[j];
    #pragma unroll
    for (int off = 1; off < 32; off <<= 1)
        term += __shfl_xor(term, off);
    if (lane == 0) {
        const float Mf = wf[32], Mb = wb[32];
        out[b] = acc - (Mf + Mb + __builtin_amdgcn_logf(term)) * LN2_F;
    }
}

extern "C" void kernel_launch(void* const* d_in, const int* in_sizes, int n_in,
                              void* d_out, int out_size, void* d_ws, size_t ws_size,
                              hipStream_t stream) {
    const float* logits   = (const float*)d_in[0];
    const float* trans    = (const float*)d_in[1];
    const int*   labels   = (const int*)d_in[2];
    const int*   seq_lens = (const int*)d_in[3];
    float* out = (float*)d_out;
    float* ws  = (float*)d_ws;    // 2048 * 33 floats = 270 KB

    // diagnostic probes first (ws results fully overwritten by chain kernel)
    crf_probe_kernel<1, 384><<<Bn * 2, 64, 0, stream>>>(logits, trans, ws);
    crf_probe_kernel<2, 384><<<Bn * 2, 64, 0, stream>>>(logits, trans, ws);
    crf_probe_kernel<4, 768><<<Bn * 2, 64, 0, stream>>>(logits, trans, ws);

    crf_chain_kernel<<<Bn * 2, 64, 0, stream>>>(logits, trans, seq_lens, ws);
    crf_combine_kernel<<<Bn, 64, 0, stream>>>(logits, trans, labels, seq_lens, ws, out);
}